// Round 5
// baseline (134.994 us; speedup 1.0000x reference)
//
#include <hip/hip_runtime.h>
#include <hip/hip_bf16.h>
#include <cstdint>

#define K_DIM 768
#define M_DIM 3072
#define BS_TOTAL 16384  // B * S
#define KT 12           // K tiles of 64

typedef __attribute__((ext_vector_type(4))) float f32x4;
typedef __attribute__((ext_vector_type(8))) short bf16x8;
typedef __attribute__((ext_vector_type(4))) unsigned short u16x4;
typedef __attribute__((ext_vector_type(4))) float fv4;

typedef unsigned int u32_g __attribute__((address_space(1)));
typedef unsigned int u32_l __attribute__((address_space(3)));

static __device__ __forceinline__ void async_load16(const void* g, void* l) {
    __builtin_amdgcn_global_load_lds((const u32_g*)g, (u32_l*)l, 16, 0, 0);
}

#define BAR() __builtin_amdgcn_s_barrier()
#define SCHEDB() __builtin_amdgcn_sched_barrier(0)

static __device__ __forceinline__ unsigned short f2bf(float f) {
    unsigned u = __builtin_bit_cast(unsigned, f);
    u += 0x7fffu + ((u >> 16) & 1u);   // RNE
    return (unsigned short)(u >> 16);
}

__global__ void densify_kernel(const float* __restrict__ values,
                               const int* __restrict__ row_offsets,
                               const int* __restrict__ column_indices,
                               unsigned short* __restrict__ Wb) {
    const int r = blockIdx.x;
    const int t = threadIdx.x;
    unsigned int* wrow32 = (unsigned int*)(Wb + (size_t)r * K_DIM);
    for (int i = t; i < K_DIM / 2; i += 256) wrow32[i] = 0u;
    __syncthreads();
    const int start = row_offsets[r], end = row_offsets[r + 1];
    unsigned short* wrow = Wb + (size_t)r * K_DIM;
    for (int i = start + t; i < end; i += 256)
        wrow[column_indices[i]] = f2bf(values[i]);
}

__global__ void convert_x_kernel(const float* __restrict__ x,
                                 unsigned short* __restrict__ xb, int n4) {
    int i = blockIdx.x * 256 + threadIdx.x;
    if (i < n4) {
        fv4 v = ((const fv4*)x)[i];
        u16x4 o;
        o[0] = f2bf(v[0]); o[1] = f2bf(v[1]); o[2] = f2bf(v[2]); o[3] = f2bf(v[3]);
        ((u16x4*)xb)[i] = o;
    }
}

// ---- Persistent: 256 blocks (1/CU), each owns 256 rows x 768 cols = 3 subtiles
// of 256x256. Per subtile: round-2's 8-wave / BK=64 / 8-phase / counted-vmcnt
// K-loop. Epilogue stores of subtile s overlap subtile s+1's prologue+phases
// (vmcnt(4) drains stores+stages together; stores are oldest in FIFO).

#define STAGE_A(buf, t, half)                                                   \
    { _Pragma("unroll") for (int c = 0; c < 2; ++c) {                           \
        const int u = c * 512 + tid;                                            \
        const int row = (half) * 128 + (u >> 3);                                \
        const int gs = (u & 7) ^ (row & 7);                                     \
        async_load16(X + (size_t)(row0 + row) * K_DIM + (t) * 64 + gs * 8,      \
                     &sm[buf][0][row * 64 + (u & 7) * 8]); } }

#define STAGE_B(buf, t, half)                                                   \
    { _Pragma("unroll") for (int c = 0; c < 2; ++c) {                           \
        const int u = c * 512 + tid;                                            \
        const int row = (half) * 128 + (u >> 3);                                \
        const int gs = (u & 7) ^ (row & 7);                                     \
        async_load16(W + (size_t)(col0 + row) * K_DIM + (t) * 64 + gs * 8,      \
                     &sm[buf][1][row * 64 + (u & 7) * 8]); } }

#define LDA(buf, mh)                                                            \
    { _Pragma("unroll") for (int mi = 0; mi < 4; ++mi) {                        \
        const int row = wm * 128 + (mh) * 64 + mi * 16 + fr;                    \
        const int sw = (row & 7) << 3;                                          \
        aq[mi][0] = *(const bf16x8*)&sm[buf][0][row * 64 + ((kq * 8) ^ sw)];    \
        aq[mi][1] = *(const bf16x8*)&sm[buf][0][row * 64 + ((32 + kq * 8) ^ sw)]; } }

#define LDB(buf, nh, breg)                                                      \
    { _Pragma("unroll") for (int ni = 0; ni < 2; ++ni) {                        \
        const int row = wn * 64 + (nh) * 32 + ni * 16 + fr;                     \
        const int sw = (row & 7) << 3;                                          \
        breg[ni][0] = *(const bf16x8*)&sm[buf][1][row * 64 + ((kq * 8) ^ sw)];  \
        breg[ni][1] = *(const bf16x8*)&sm[buf][1][row * 64 + ((32 + kq * 8) ^ sw)]; } }

#define MFMA16(mh, nh, breg)                                                    \
    { __builtin_amdgcn_s_setprio(1);                                            \
      _Pragma("unroll") for (int mi = 0; mi < 4; ++mi)                          \
      _Pragma("unroll") for (int ni = 0; ni < 2; ++ni) {                        \
        acc[(mh)*4+mi][(nh)*2+ni] = __builtin_amdgcn_mfma_f32_16x16x32_bf16(    \
            aq[mi][0], breg[ni][0], acc[(mh)*4+mi][(nh)*2+ni], 0, 0, 0);        \
        acc[(mh)*4+mi][(nh)*2+ni] = __builtin_amdgcn_mfma_f32_16x16x32_bf16(    \
            aq[mi][1], breg[ni][1], acc[(mh)*4+mi][(nh)*2+ni], 0, 0, 0); }      \
      __builtin_amdgcn_s_setprio(0); }

__global__ __launch_bounds__(512, 2) void gemm_kernel(
    const unsigned short* __restrict__ X,
    const unsigned short* __restrict__ W,
    const float* __restrict__ bias,
    float* __restrict__ out) {
    __shared__ __align__(16) unsigned short sm[2][2][256 * 64];  // 128 KiB

    // 256 blocks: XCD gets 8 contiguous row-panels (A working set 3 MB < L2)
    const int bid = blockIdx.x;           // 0..255
    const int xcd = bid & 7;
    const int j   = bid >> 3;             // 0..31
    const int by  = xcd * 8 + (j >> 2);   // 0..63
    const int bx  = j & 3;                // 0..3
    const int row0    = by * 256;
    const int colbase = bx * 768;

    const int tid  = threadIdx.x;
    const int lane = tid & 63;
    const int wave = tid >> 6;
    const int wm = wave >> 2;   // 0..1 -> A rows wm*128..+127
    const int wn = wave & 3;    // 0..3 -> B rows wn*64..+63
    const int fr = lane & 15;
    const int kq = lane >> 4;   // 0..3

    bf16x8 aq[4][2], b0[2][2], b1[2][2];

    for (int s = 0; s < 3; ++s) {
        const int col0 = colbase + s * 256;
        f32x4 acc[8][4] = {};

        // prologue: tile 0 fully + B of tile 1
        STAGE_A(0, 0, 0); STAGE_A(0, 0, 1);
        STAGE_B(0, 0, 0); STAGE_B(0, 0, 1);
        STAGE_B(1, 1, 0); STAGE_B(1, 1, 1);
        // bias for this subtile (drained by the vmcnt(4) below)
        float bv[4];
#pragma unroll
        for (int ni = 0; ni < 4; ++ni) bv[ni] = bias[col0 + wn * 64 + ni * 16 + fr];
        // drains: prior subtile's 64 stores + tile0 stages; leaves B(1) in flight
        asm volatile("s_waitcnt vmcnt(4)" ::: "memory");
        SCHEDB();
        BAR();

        for (int t = 0; t < KT; ++t) {
            const int buf = t & 1, nbuf = buf ^ 1;
            // P0: (mh0, nh0)
            LDA(buf, 0);
            LDB(buf, 0, b0);
            if (t + 1 < KT) STAGE_A(nbuf, t + 1, 0);
            BAR();
            MFMA16(0, 0, b0);
            BAR();
            // P1: (mh0, nh1)
            LDB(buf, 1, b1);
            if (t + 1 < KT) STAGE_A(nbuf, t + 1, 1);
            BAR();
            MFMA16(0, 1, b1);
            BAR();
            // P2: (mh1, nh1)
            LDA(buf, 1);
            if (t + 2 < KT) STAGE_B(buf, t + 2, 0);
            BAR();
            MFMA16(1, 1, b1);
            BAR();
            // P3: (mh1, nh0)
            if (t + 2 < KT) STAGE_B(buf, t + 2, 1);
            BAR();
            MFMA16(1, 0, b0);
            if (t + 2 < KT)      { asm volatile("s_waitcnt vmcnt(4)" ::: "memory"); SCHEDB(); }
            else if (t + 1 < KT) { asm volatile("s_waitcnt vmcnt(0)" ::: "memory"); SCHEDB(); }
            BAR();
        }

        // epilogue: frag row = kq*4 + j, col = fr; stores overlap next subtile
        const int orow0 = row0 + wm * 128 + kq * 4;
#pragma unroll
        for (int mi = 0; mi < 8; ++mi)
#pragma unroll
            for (int jj = 0; jj < 4; ++jj) {
                float* op = out + (size_t)(orow0 + mi * 16 + jj) * M_DIM + col0 + wn * 64 + fr;
#pragma unroll
                for (int ni = 0; ni < 4; ++ni)
                    __builtin_nontemporal_store(acc[mi][ni][jj] + bv[ni], op + ni * 16);
            }
    }
}

extern "C" void kernel_launch(void* const* d_in, const int* in_sizes, int n_in,
                              void* d_out, int out_size, void* d_ws, size_t ws_size,
                              hipStream_t stream) {
    const float* values         = (const float*)d_in[0];
    const float* bias           = (const float*)d_in[1];
    const float* x              = (const float*)d_in[2];
    const int*   row_offsets    = (const int*)d_in[4];
    const int*   column_indices = (const int*)d_in[5];

    unsigned short* Wb = (unsigned short*)d_ws;
    unsigned short* Xb = (unsigned short*)((char*)d_ws + (size_t)M_DIM * K_DIM * 2);

    densify_kernel<<<M_DIM, 256, 0, stream>>>(values, row_offsets, column_indices, Wb);

    const int n4 = BS_TOTAL * K_DIM / 4;
    convert_x_kernel<<<(n4 + 255) / 256, 256, 0, stream>>>(x, Xb, n4);

    gemm_kernel<<<256, 512, 0, stream>>>(Xb, Wb, bias, (float*)d_out);
}

// Round 6
// 133.746 us; speedup vs baseline: 1.0093x; 1.0093x over previous
//
#include <hip/hip_runtime.h>
#include <hip/hip_bf16.h>
#include <cstdint>

#define K_DIM 768
#define M_DIM 3072
#define BS_TOTAL 16384  // B * S
#define BM 128
#define BN 256
#define BK 32
#define KT 24           // K_DIM / BK

typedef __attribute__((ext_vector_type(4))) float f32x4;
typedef __attribute__((ext_vector_type(8))) short bf16x8;
typedef __attribute__((ext_vector_type(4))) unsigned short u16x4;
typedef __attribute__((ext_vector_type(4))) float fv4;

typedef unsigned int u32_g __attribute__((address_space(1)));
typedef unsigned int u32_l __attribute__((address_space(3)));

static __device__ __forceinline__ void async_load16(const void* g, void* l) {
    __builtin_amdgcn_global_load_lds((const u32_g*)g, (u32_l*)l, 16, 0, 0);
}

#define BAR() __builtin_amdgcn_s_barrier()
#define SCHEDB() __builtin_amdgcn_sched_barrier(0)

static __device__ __forceinline__ unsigned short f2bf(float f) {
    unsigned u = __builtin_bit_cast(unsigned, f);
    u += 0x7fffu + ((u >> 16) & 1u);   // RNE
    return (unsigned short)(u >> 16);
}

// Merged prep: blocks [0, M_DIM) densify W rows; blocks [M_DIM, ...) convert x.
__global__ void prep_kernel(const float* __restrict__ values,
                            const int* __restrict__ row_offsets,
                            const int* __restrict__ column_indices,
                            unsigned short* __restrict__ Wb,
                            const float* __restrict__ x,
                            unsigned short* __restrict__ xb, int n4) {
    const int b = blockIdx.x;
    const int t = threadIdx.x;
    if (b < M_DIM) {
        const int r = b;
        unsigned int* wrow32 = (unsigned int*)(Wb + (size_t)r * K_DIM);
        for (int i = t; i < K_DIM / 2; i += 256) wrow32[i] = 0u;
        __syncthreads();
        const int start = row_offsets[r], end = row_offsets[r + 1];
        unsigned short* wrow = Wb + (size_t)r * K_DIM;
        for (int i = start + t; i < end; i += 256)
            wrow[column_indices[i]] = f2bf(values[i]);
    } else {
        const int i = (b - M_DIM) * 256 + t;
        if (i < n4) {
            fv4 v = ((const fv4*)x)[i];
            u16x4 o;
            o[0] = f2bf(v[0]); o[1] = f2bf(v[1]); o[2] = f2bf(v[2]); o[3] = f2bf(v[3]);
            ((u16x4*)xb)[i] = o;
        }
    }
}

// ---- BM=128 x BN=256, BK=32, 4 waves (1Mx4N, wave-tile 128x64), triple-buffered
// LDS (72 KiB) -> 2 blocks/CU. 2-ahead prefetch, counted vmcnt(6), 1 barrier/tile.
// Swizzle: 16B-block idx ^= (row>>1)&3 (0 conflicts measured R3/R4); linear
// global_load_lds dest, involution on global source + ds_read addr (rule 21).

#define STAGE_A(buf, t)                                                         \
    { _Pragma("unroll") for (int c = 0; c < 2; ++c) {                           \
        const int u = c * 256 + tid;                                            \
        const int row = u >> 2;                                                 \
        const int gs = (u & 3) ^ ((row >> 1) & 3);                              \
        async_load16(X + (size_t)(row0 + row) * K_DIM + (t) * BK + gs * 8,      \
                     &sa[buf][(size_t)u * 8]); } }

#define STAGE_B(buf, t)                                                         \
    { _Pragma("unroll") for (int c = 0; c < 4; ++c) {                           \
        const int u = c * 256 + tid;                                            \
        const int row = u >> 2;                                                 \
        const int gs = (u & 3) ^ ((row >> 1) & 3);                              \
        async_load16(W + (size_t)(col0 + row) * K_DIM + (t) * BK + gs * 8,      \
                     &sb[buf][(size_t)u * 8]); } }

#define LDA(buf)                                                                \
    { _Pragma("unroll") for (int mi = 0; mi < 8; ++mi) {                        \
        const int row = mi * 16 + fr;                                           \
        const int blk = kq ^ ((row >> 1) & 3);                                  \
        aq[mi] = *(const bf16x8*)&sa[buf][row * BK + blk * 8]; } }

#define LDB(buf)                                                                \
    { _Pragma("unroll") for (int ni = 0; ni < 4; ++ni) {                        \
        const int row = wn * 64 + ni * 16 + fr;                                 \
        const int blk = kq ^ ((row >> 1) & 3);                                  \
        bq[ni] = *(const bf16x8*)&sb[buf][row * BK + blk * 8]; } }

#define MFMA32()                                                                \
    { __builtin_amdgcn_s_setprio(1);                                            \
      _Pragma("unroll") for (int mi = 0; mi < 8; ++mi)                          \
      _Pragma("unroll") for (int ni = 0; ni < 4; ++ni)                          \
        acc[mi][ni] = __builtin_amdgcn_mfma_f32_16x16x32_bf16(                  \
            aq[mi], bq[ni], acc[mi][ni], 0, 0, 0);                              \
      __builtin_amdgcn_s_setprio(0); }

__global__ __launch_bounds__(256, 2) void gemm_kernel(
    const unsigned short* __restrict__ X,
    const unsigned short* __restrict__ W,
    const float* __restrict__ bias,
    float* __restrict__ out) {
    __shared__ __align__(16) unsigned short sa[3][BM * BK];  // 24 KiB
    __shared__ __align__(16) unsigned short sb[3][BN * BK];  // 48 KiB

    // XCD swizzle (nwg = 1536, divisible by 8), then COLUMN-major block order:
    // contiguous bids within an XCD share one B col-panel (~0.4 MB, L2-resident).
    const int nwg = gridDim.x;
    int bid = blockIdx.x;
    bid = (bid & 7) * (nwg >> 3) + (bid >> 3);
    const int by = bid % (BS_TOTAL / BM);   // 128 row tiles (fast)
    const int bx = bid / (BS_TOTAL / BM);   // 12 col tiles (slow)
    const int row0 = by * BM;
    const int col0 = bx * BN;

    const int tid  = threadIdx.x;
    const int lane = tid & 63;
    const int wn   = tid >> 6;    // 0..3: B rows wn*64..+63
    const int fr   = lane & 15;
    const int kq   = lane >> 4;   // 0..3

    f32x4 acc[8][4] = {};
    bf16x8 aq[8], bq[4];

    // bias (4 VMEM loads, oldest in FIFO — vmcnt(6) analysis still drains tile 0)
    float bv[4];
#pragma unroll
    for (int ni = 0; ni < 4; ++ni) bv[ni] = bias[col0 + wn * 64 + ni * 16 + fr];

    // prologue: stage tiles 0 and 1
    STAGE_A(0, 0); STAGE_B(0, 0);
    STAGE_A(1, 1); STAGE_B(1, 1);
    asm volatile("s_waitcnt vmcnt(6)" ::: "memory");  // tile 0 complete
    SCHEDB();
    BAR();

    for (int t = 0; t < KT; ++t) {
        const int buf = t % 3;
        // issue 2-ahead stage first (VMEM pipe), then this tile's ds_reads
        if (t + 2 < KT) {
            const int pbuf = (t + 2) % 3;
            STAGE_A(pbuf, t + 2); STAGE_B(pbuf, t + 2);
        }
        LDA(buf);
        LDB(buf);
        MFMA32();
        // counted: drains t+1's stages (t+2's stay in flight); never 0 steady-state
        if (t + 2 < KT)      { asm volatile("s_waitcnt vmcnt(6)" ::: "memory"); SCHEDB(); }
        else if (t + 1 < KT) { asm volatile("s_waitcnt vmcnt(0)" ::: "memory"); SCHEDB(); }
        BAR();
    }

    // epilogue: frag row = kq*4 + j, col = fr (m89-verified C/D layout)
    const int orow0 = row0 + kq * 4;
#pragma unroll
    for (int mi = 0; mi < 8; ++mi)
#pragma unroll
        for (int j = 0; j < 4; ++j) {
            float* op = out + (size_t)(orow0 + mi * 16 + j) * M_DIM + col0 + wn * 64 + fr;
#pragma unroll
            for (int ni = 0; ni < 4; ++ni)
                __builtin_nontemporal_store(acc[mi][ni][j] + bv[ni], op + ni * 16);
        }
}

extern "C" void kernel_launch(void* const* d_in, const int* in_sizes, int n_in,
                              void* d_out, int out_size, void* d_ws, size_t ws_size,
                              hipStream_t stream) {
    const float* values         = (const float*)d_in[0];
    const float* bias           = (const float*)d_in[1];
    const float* x              = (const float*)d_in[2];
    const int*   row_offsets    = (const int*)d_in[4];
    const int*   column_indices = (const int*)d_in[5];

    unsigned short* Wb = (unsigned short*)d_ws;
    unsigned short* Xb = (unsigned short*)((char*)d_ws + (size_t)M_DIM * K_DIM * 2);

    const int n4 = BS_TOTAL * K_DIM / 4;
    const int prep_blocks = M_DIM + (n4 + 255) / 256;
    prep_kernel<<<prep_blocks, 256, 0, stream>>>(values, row_offsets, column_indices,
                                                 Wb, x, Xb, n4);

    const int grid = (BS_TOTAL / BM) * (M_DIM / BN);  // 128 * 12 = 1536
    gemm_kernel<<<grid, 256, 0, stream>>>(Xb, Wb, bias, (float*)d_out);
}